// Round 5
// baseline (4982.773 us; speedup 1.0000x reference)
//
#include <hip/hip_runtime.h>
#include <hip/hip_bf16.h>

// ATTRIBUTION ROUND: per-rep-identical internal replication so each major kernel's
// dispatch exceeds the ~320us harness poison fills and surfaces in the top-5 rocprof
// rows with its own counters. Per-rep code identical to R4. Deterministic.
#define BB 32
#define CC 2048
#define LL 891
#define PP 8
#define HIDN 8192
#define NOUT 16384

typedef __attribute__((ext_vector_type(4))) float f32x4;
typedef __attribute__((ext_vector_type(8))) __bf16 bf16x8;

// ---------- kernel 1: global average pool, one wave per (b,c) row, float4 body ----------
__global__ __launch_bounds__(256) void pool_kernel(const float* __restrict__ x,
                                                   __hip_bfloat16* __restrict__ pooled,
                                                   int reps) {
  int wid = threadIdx.x >> 6, lane = threadIdx.x & 63;
  int row = blockIdx.x * 4 + wid;  // < 65536
  const float* r = x + (long)row * LL;
  int align = (4 - ((row * 3) & 3)) & 3;       // scalar head elements (891%4==3)
  int nvec = (LL - align) >> 2;                // float4 count
  int rem = LL - align - (nvec << 2);          // scalar tail
  const f32x4* v = (const f32x4*)(r + align);
  for (int rep = 0; rep < reps; ++rep) {
    float s = 0.f;
    for (int i = lane; i < nvec; i += 64) {
      f32x4 q = v[i];
      s += (q.x + q.y) + (q.z + q.w);
    }
    if (lane < align) s += r[lane];
    if (lane < rem) s += r[align + (nvec << 2) + lane];
#pragma unroll
    for (int off = 32; off > 0; off >>= 1) s += __shfl_xor(s, off);
    if (lane == 0) pooled[row] = __float2bfloat16(s * (1.0f / (float)LL));
    asm volatile("" ::: "memory");
  }
}

// ---------- non-temporal 16B load ----------
__device__ __forceinline__ f32x4 ldnt(const float* p) {
  return __builtin_nontemporal_load((const f32x4*)p);
}

__device__ __forceinline__ bf16x8 cvt8(f32x4 a, f32x4 b) {
  bf16x8 r;
  r[0] = (__bf16)a.x; r[1] = (__bf16)a.y; r[2] = (__bf16)a.z; r[3] = (__bf16)a.w;
  r[4] = (__bf16)b.x; r[5] = (__bf16)b.y; r[6] = (__bf16)b.z; r[7] = (__bf16)b.w;
  return r;
}

// ---------- kernels 2/4: partial[32][N] = A[32][K](bf16) @ W[N][K](f32->bf16)^T ----------
__global__ __launch_bounds__(256) void fc_kernel(const __hip_bfloat16* __restrict__ A,
                                                 const float* __restrict__ W,
                                                 float* __restrict__ partial,
                                                 int N, int K, int kc, int reps) {
  int lane = threadIdx.x & 63, wv = threadIdx.x >> 6;
  int n0 = blockIdx.x * 64 + wv * 16;
  int k0 = blockIdx.y * kc;
  int r = lane & 15, kg = lane >> 4;

  const float* Wp = W + (long)(n0 + r) * K + k0 + kg * 8;
  const __hip_bfloat16* Ap0 = A + (long)r * K + k0 + kg * 8;
  const __hip_bfloat16* Ap1 = Ap0 + 16 * (long)K;
  long base = (long)blockIdx.y * 32 * N + n0 + r;

  for (int rep = 0; rep < reps; ++rep) {
    f32x4 acc0 = {0.f, 0.f, 0.f, 0.f};
    f32x4 acc1 = {0.f, 0.f, 0.f, 0.f};
#pragma unroll 4
    for (int ks = 0; ks < kc; ks += 32) {
      f32x4 w0 = ldnt(Wp + ks);
      f32x4 w1 = ldnt(Wp + ks + 4);
      int4 a0 = *(const int4*)(Ap0 + ks);
      int4 a1 = *(const int4*)(Ap1 + ks);
      bf16x8 bv = cvt8(w0, w1);
      acc0 = __builtin_amdgcn_mfma_f32_16x16x32_bf16(__builtin_bit_cast(bf16x8, a0), bv, acc0, 0, 0, 0);
      acc1 = __builtin_amdgcn_mfma_f32_16x16x32_bf16(__builtin_bit_cast(bf16x8, a1), bv, acc1, 0, 0, 0);
    }
#pragma unroll
    for (int j = 0; j < 4; ++j) {
      int row = kg * 4 + j;
      partial[base + (long)row * N] = acc0[j];
      partial[base + (long)(row + 16) * N] = acc1[j];
    }
    asm volatile("" ::: "memory");
  }
}

// ---------- kernels 3/5: reduce splits + bias + sigmoid, float4-wide ----------
__global__ __launch_bounds__(256) void fc_reduce_kernel(const float* __restrict__ part,
                                                        int nsplit, int MN, int N,
                                                        const float* __restrict__ bias,
                                                        float* __restrict__ outF,
                                                        __hip_bfloat16* __restrict__ outB) {
  int i4 = blockIdx.x * 256 + threadIdx.x;
  if (i4 * 4 >= MN) return;
  f32x4 s = {0.f, 0.f, 0.f, 0.f};
  for (int i = 0; i < nsplit; ++i) {
    f32x4 v = *(const f32x4*)(part + (long)i * MN + i4 * 4);
    s += v;
  }
  f32x4 bv = *(const f32x4*)(bias + ((i4 * 4) & (N - 1)));
  f32x4 g;
  g.x = 1.f / (1.f + __expf(-(s.x + bv.x)));
  g.y = 1.f / (1.f + __expf(-(s.y + bv.y)));
  g.z = 1.f / (1.f + __expf(-(s.z + bv.z)));
  g.w = 1.f / (1.f + __expf(-(s.w + bv.w)));
  if (outF) *(f32x4*)(outF + i4 * 4) = g;
  if (outB) {
    union { __hip_bfloat16 h[4]; unsigned long long u; } pk;
    pk.h[0] = __float2bfloat16(g.x); pk.h[1] = __float2bfloat16(g.y);
    pk.h[2] = __float2bfloat16(g.z); pk.h[3] = __float2bfloat16(g.w);
    *((unsigned long long*)outB + i4) = pk.u;
  }
}

// ---------- kernel 6: weighted partials ----------
__global__ __launch_bounds__(256) void ein_partial_kernel(const float* __restrict__ x,
                                                          const float* __restrict__ g,
                                                          float* __restrict__ part,
                                                          int reps) {
  int l = blockIdx.x * 256 + threadIdx.x;
  int b = blockIdx.y;
  int s = blockIdx.z;
  int c0 = s * 256;
  const float* xp = x + ((long)b * CC + c0) * LL + l;
  const float* gp = g + (long)b * NOUT + c0;
  bool act = l < LL;
  for (int rep = 0; rep < reps; ++rep) {
    float acc[PP] = {0.f, 0.f, 0.f, 0.f, 0.f, 0.f, 0.f, 0.f};
#pragma unroll 8
    for (int i = 0; i < 256; ++i) {
      float xv = act ? xp[(long)i * LL] : 0.f;
#pragma unroll
      for (int p = 0; p < PP; ++p) acc[p] += gp[p * CC + i] * xv;
    }
    if (act) {
      float* pp = part + (long)(s * BB + b) * PP * LL + l;
#pragma unroll
      for (int p = 0; p < PP; ++p) pp[(long)p * LL] = acc[p];
    }
    asm volatile("" ::: "memory");
  }
}

// ---------- kernel 7: reduce c-splits, /C, float4-wide ----------
__global__ __launch_bounds__(256) void ein_reduce_kernel(const float* __restrict__ part,
                                                         float* __restrict__ outw) {
  int i4 = blockIdx.x * 256 + threadIdx.x;
  if (i4 >= (BB * PP * LL) / 4) return;
  f32x4 s = {0.f, 0.f, 0.f, 0.f};
#pragma unroll
  for (int i = 0; i < 8; ++i) {
    f32x4 v = *(const f32x4*)(part + (long)i * (BB * PP * LL) + i4 * 4);
    s += v;
  }
  const float inv = 1.0f / (float)CC;
  f32x4 o = s * inv;
  *(f32x4*)(outw + i4 * 4) = o;
}

extern "C" void kernel_launch(void* const* d_in, const int* in_sizes, int n_in,
                              void* d_out, int out_size, void* d_ws, size_t ws_size,
                              hipStream_t stream) {
  const float* x     = (const float*)d_in[0];
  const float* fc1_w = (const float*)d_in[1];
  const float* fc1_b = (const float*)d_in[2];
  const float* fc2_w = (const float*)d_in[3];
  const float* fc2_b = (const float*)d_in[4];
  float* out = (float*)d_out;

  char* ws = (char*)d_ws;
  __hip_bfloat16* pooled = (__hip_bfloat16*)ws;
  __hip_bfloat16* hbuf   = (__hip_bfloat16*)(ws + 131072);
  float* part            = (float*)(ws + 655360);

  // Rep counts: each major kernel's dispatch must exceed ~330us to beat the
  // poison fills into the top-5. pool x32, fc1 x96, fc2 x6, ein x32.
  pool_kernel<<<BB * CC / 4, 256, 0, stream>>>(x, pooled, 32);

  fc_kernel<<<dim3(HIDN / 64, 8), 256, 0, stream>>>(pooled, fc1_w, part, HIDN, CC, CC / 8, 96);
  fc_reduce_kernel<<<BB * HIDN / 1024, 256, 0, stream>>>(part, 8, BB * HIDN, HIDN, fc1_b,
                                                         nullptr, hbuf);

  fc_kernel<<<dim3(NOUT / 64, 8), 256, 0, stream>>>(hbuf, fc2_w, part, NOUT, HIDN, HIDN / 8, 6);
  fc_reduce_kernel<<<BB * NOUT / 1024, 256, 0, stream>>>(part, 8, BB * NOUT, NOUT, fc2_b,
                                                         out, nullptr);

  ein_partial_kernel<<<dim3(4, BB, 8), 256, 0, stream>>>(x, out, part, 32);
  ein_reduce_kernel<<<(BB * PP * LL / 4 + 255) / 256, 256, 0, stream>>>(part, out + BB * PP * CC);
}

// Round 7
// 275.319 us; speedup vs baseline: 18.0982x; 18.0982x over previous
//
#include <hip/hip_runtime.h>
#include <hip/hip_bf16.h>

// channel_cluster_layer: pool -> fc1(sigmoid) -> fc2(sigmoid) -> weighted channel reduce
// B=32, C=2048, L=891 (9*11*9), P=8, HID=8192, NOUT=16384
// R5 finding: fc_kernel was LATENCY-bound (VGPR=28, hbm 15%, MfmaUtil 2%) -- compiler
// kept no loads in flight. R6: explicit depth-2 register pipeline + 2 n-tiles/wave.
#define BB 32
#define CC 2048
#define LL 891
#define PP 8
#define HIDN 8192
#define NOUT 16384

typedef __attribute__((ext_vector_type(4))) float f32x4;
typedef __attribute__((ext_vector_type(8))) __bf16 bf16x8;

// ---------- kernel 1: global average pool, one wave per (b,c) row, float4 body ----------
__global__ __launch_bounds__(256) void pool_kernel(const float* __restrict__ x,
                                                   __hip_bfloat16* __restrict__ pooled) {
  int wid = threadIdx.x >> 6, lane = threadIdx.x & 63;
  int row = blockIdx.x * 4 + wid;  // < 65536
  const float* r = x + (long)row * LL;
  int align = (4 - ((row * 3) & 3)) & 3;       // scalar head elements (891%4==3)
  int nvec = (LL - align) >> 2;                // float4 count
  int rem = LL - align - (nvec << 2);          // scalar tail
  const f32x4* v = (const f32x4*)(r + align);
  float s = 0.f;
  for (int i = lane; i < nvec; i += 64) {
    f32x4 q = v[i];
    s += (q.x + q.y) + (q.z + q.w);
  }
  if (lane < align) s += r[lane];
  if (lane < rem) s += r[align + (nvec << 2) + lane];
#pragma unroll
  for (int off = 32; off > 0; off >>= 1) s += __shfl_xor(s, off);
  if (lane == 0) pooled[row] = __float2bfloat16(s * (1.0f / (float)LL));
}

// ---------- non-temporal 16B load (no cache allocate; protects x residency in L3) ----------
__device__ __forceinline__ f32x4 ldnt(const float* p) {
  return __builtin_nontemporal_load((const f32x4*)p);
}

// f32x8 -> bf16x8 via native casts (compiler emits v_cvt_pk_bf16_f32, RNE)
__device__ __forceinline__ bf16x8 cvt8(f32x4 a, f32x4 b) {
  bf16x8 r;
  r[0] = (__bf16)a.x; r[1] = (__bf16)a.y; r[2] = (__bf16)a.z; r[3] = (__bf16)a.w;
  r[4] = (__bf16)b.x; r[5] = (__bf16)b.y; r[6] = (__bf16)b.z; r[7] = (__bf16)b.w;
  return r;
}

// ---------- kernels 2/4: partial[32][N] = A[32][K](bf16) @ W[N][K](f32->bf16)^T ----------
// Each wave: TWO independent 16-row n-tiles (n0, n0+64), shared A fragments.
// Depth-2 register pipeline: next k-step's 6 loads issued before current step's MFMAs.
// grid: (N/128, nsplit); block 256 = 4 waves; block covers 128 n-rows.
__global__ __launch_bounds__(256) void fc_kernel(const __hip_bfloat16* __restrict__ A,
                                                 const float* __restrict__ W,
                                                 float* __restrict__ partial,
                                                 int N, int K, int kc) {
  int lane = threadIdx.x & 63, wv = threadIdx.x >> 6;
  int n0 = blockIdx.x * 128 + wv * 16;  // tile 0
  int k0 = blockIdx.y * kc;
  int r = lane & 15, kg = lane >> 4;

  const float* Wp0 = W + (long)(n0 + r) * K + k0 + kg * 8;
  const float* Wp1 = Wp0 + 64 * (long)K;                    // tile 1 = n0+64
  const __hip_bfloat16* Ap0 = A + (long)r * K + k0 + kg * 8;
  const __hip_bfloat16* Ap1 = Ap0 + 16 * (long)K;

  f32x4 acc00 = {0.f, 0.f, 0.f, 0.f};  // b 0-15  x tile0
  f32x4 acc01 = {0.f, 0.f, 0.f, 0.f};  // b 16-31 x tile0
  f32x4 acc10 = {0.f, 0.f, 0.f, 0.f};  // b 0-15  x tile1
  f32x4 acc11 = {0.f, 0.f, 0.f, 0.f};  // b 16-31 x tile1

  // prologue: step-0 loads
  f32x4 w0a = ldnt(Wp0), w0b = ldnt(Wp0 + 4);
  f32x4 w1a = ldnt(Wp1), w1b = ldnt(Wp1 + 4);
  int4 a0 = *(const int4*)(Ap0);
  int4 a1 = *(const int4*)(Ap1);

  for (int ks = 32; ks < kc; ks += 32) {
    // issue next step's loads (depth-2 pipeline)
    f32x4 nw0a = ldnt(Wp0 + ks), nw0b = ldnt(Wp0 + ks + 4);
    f32x4 nw1a = ldnt(Wp1 + ks), nw1b = ldnt(Wp1 + ks + 4);
    int4 na0 = *(const int4*)(Ap0 + ks);
    int4 na1 = *(const int4*)(Ap1 + ks);
    // compute current step
    bf16x8 b0 = cvt8(w0a, w0b);
    bf16x8 b1 = cvt8(w1a, w1b);
    bf16x8 va0 = __builtin_bit_cast(bf16x8, a0);
    bf16x8 va1 = __builtin_bit_cast(bf16x8, a1);
    acc00 = __builtin_amdgcn_mfma_f32_16x16x32_bf16(va0, b0, acc00, 0, 0, 0);
    acc01 = __builtin_amdgcn_mfma_f32_16x16x32_bf16(va1, b0, acc01, 0, 0, 0);
    acc10 = __builtin_amdgcn_mfma_f32_16x16x32_bf16(va0, b1, acc10, 0, 0, 0);
    acc11 = __builtin_amdgcn_mfma_f32_16x16x32_bf16(va1, b1, acc11, 0, 0, 0);
    // rotate
    w0a = nw0a; w0b = nw0b; w1a = nw1a; w1b = nw1b; a0 = na0; a1 = na1;
  }
  // epilogue: last step
  {
    bf16x8 b0 = cvt8(w0a, w0b);
    bf16x8 b1 = cvt8(w1a, w1b);
    bf16x8 va0 = __builtin_bit_cast(bf16x8, a0);
    bf16x8 va1 = __builtin_bit_cast(bf16x8, a1);
    acc00 = __builtin_amdgcn_mfma_f32_16x16x32_bf16(va0, b0, acc00, 0, 0, 0);
    acc01 = __builtin_amdgcn_mfma_f32_16x16x32_bf16(va1, b0, acc01, 0, 0, 0);
    acc10 = __builtin_amdgcn_mfma_f32_16x16x32_bf16(va0, b1, acc10, 0, 0, 0);
    acc11 = __builtin_amdgcn_mfma_f32_16x16x32_bf16(va1, b1, acc11, 0, 0, 0);
  }

  // C/D layout (m89-verified): col = lane&15 (-> n), row = (lane>>4)*4 + reg (-> b)
  long base = (long)blockIdx.y * 32 * N + n0 + r;
#pragma unroll
  for (int j = 0; j < 4; ++j) {
    int row = kg * 4 + j;
    partial[base + (long)row * N] = acc00[j];
    partial[base + (long)(row + 16) * N] = acc01[j];
    partial[base + 64 + (long)row * N] = acc10[j];
    partial[base + 64 + (long)(row + 16) * N] = acc11[j];
  }
}

// ---------- kernels 3/5: reduce splits + bias + sigmoid, float4-wide ----------
__global__ __launch_bounds__(256) void fc_reduce_kernel(const float* __restrict__ part,
                                                        int nsplit, int MN, int N,
                                                        const float* __restrict__ bias,
                                                        float* __restrict__ outF,
                                                        __hip_bfloat16* __restrict__ outB) {
  int i4 = blockIdx.x * 256 + threadIdx.x;  // MN/4 lanes
  if (i4 * 4 >= MN) return;
  f32x4 s = {0.f, 0.f, 0.f, 0.f};
  for (int i = 0; i < nsplit; ++i) {
    f32x4 v = *(const f32x4*)(part + (long)i * MN + i4 * 4);
    s += v;
  }
  f32x4 bv = *(const f32x4*)(bias + ((i4 * 4) & (N - 1)));
  f32x4 g;
  g.x = 1.f / (1.f + __expf(-(s.x + bv.x)));
  g.y = 1.f / (1.f + __expf(-(s.y + bv.y)));
  g.z = 1.f / (1.f + __expf(-(s.z + bv.z)));
  g.w = 1.f / (1.f + __expf(-(s.w + bv.w)));
  if (outF) *(f32x4*)(outF + i4 * 4) = g;
  if (outB) {
    union { __hip_bfloat16 h[4]; unsigned long long u; } pk;
    pk.h[0] = __float2bfloat16(g.x); pk.h[1] = __float2bfloat16(g.y);
    pk.h[2] = __float2bfloat16(g.z); pk.h[3] = __float2bfloat16(g.w);
    *((unsigned long long*)outB + i4) = pk.u;
  }
}

// ---------- kernel 6: weighted[b][p][l] partials = sum_c g[b][p*C+c] * x[b][c][l] ----------
__global__ __launch_bounds__(256) void ein_partial_kernel(const float* __restrict__ x,
                                                          const float* __restrict__ g,
                                                          float* __restrict__ part) {
  int l = blockIdx.x * 256 + threadIdx.x;
  int b = blockIdx.y;
  int s = blockIdx.z;
  int c0 = s * 256;
  const float* xp = x + ((long)b * CC + c0) * LL + l;
  const float* gp = g + (long)b * NOUT + c0;
  bool act = l < LL;
  float acc[PP] = {0.f, 0.f, 0.f, 0.f, 0.f, 0.f, 0.f, 0.f};
#pragma unroll 8
  for (int i = 0; i < 256; ++i) {
    float xv = act ? xp[(long)i * LL] : 0.f;
#pragma unroll
    for (int p = 0; p < PP; ++p) acc[p] += gp[p * CC + i] * xv;
  }
  if (act) {
    float* pp = part + (long)(s * BB + b) * PP * LL + l;
#pragma unroll
    for (int p = 0; p < PP; ++p) pp[(long)p * LL] = acc[p];
  }
}

// ---------- kernel 7: reduce c-splits, /C, float4-wide ----------
__global__ __launch_bounds__(256) void ein_reduce_kernel(const float* __restrict__ part,
                                                         float* __restrict__ outw) {
  int i4 = blockIdx.x * 256 + threadIdx.x;  // 57024 = 891*256/4 lanes
  if (i4 >= (BB * PP * LL) / 4) return;
  f32x4 s = {0.f, 0.f, 0.f, 0.f};
#pragma unroll
  for (int i = 0; i < 8; ++i) {
    f32x4 v = *(const f32x4*)(part + (long)i * (BB * PP * LL) + i4 * 4);
    s += v;
  }
  const float inv = 1.0f / (float)CC;
  f32x4 o = s * inv;
  *(f32x4*)(outw + i4 * 4) = o;
}

extern "C" void kernel_launch(void* const* d_in, const int* in_sizes, int n_in,
                              void* d_out, int out_size, void* d_ws, size_t ws_size,
                              hipStream_t stream) {
  const float* x     = (const float*)d_in[0];
  const float* fc1_w = (const float*)d_in[1];
  const float* fc1_b = (const float*)d_in[2];
  const float* fc2_w = (const float*)d_in[3];
  const float* fc2_b = (const float*)d_in[4];
  float* out = (float*)d_out;

  char* ws = (char*)d_ws;
  __hip_bfloat16* pooled = (__hip_bfloat16*)ws;              // 32*2048*2   = 128 KB
  __hip_bfloat16* hbuf   = (__hip_bfloat16*)(ws + 131072);   // 32*8192*2   = 512 KB
  float* part            = (float*)(ws + 655360);            // max 16.8 MB (reused per stage)

  pool_kernel<<<BB * CC / 4, 256, 0, stream>>>(x, pooled);

  // fc1: N=8192, K=2048, 8-way split-K (kc=256); blocks cover 128 n-rows -> 512 blocks
  fc_kernel<<<dim3(HIDN / 128, 8), 256, 0, stream>>>(pooled, fc1_w, part, HIDN, CC, CC / 8);
  fc_reduce_kernel<<<BB * HIDN / 1024, 256, 0, stream>>>(part, 8, BB * HIDN, HIDN, fc1_b,
                                                         nullptr, hbuf);

  // fc2: N=16384, K=8192, 8-way split-K (kc=1024) -> 1024 blocks
  fc_kernel<<<dim3(NOUT / 128, 8), 256, 0, stream>>>(hbuf, fc2_w, part, NOUT, HIDN, HIDN / 8);
  fc_reduce_kernel<<<BB * NOUT / 1024, 256, 0, stream>>>(part, 8, BB * NOUT, NOUT, fc2_b,
                                                         out, nullptr);

  ein_partial_kernel<<<dim3(4, BB, 8), 256, 0, stream>>>(x, out, part);
  ein_reduce_kernel<<<(BB * PP * LL / 4 + 255) / 256, 256, 0, stream>>>(part, out + BB * PP * CC);
}

// Round 8
// 257.248 us; speedup vs baseline: 19.3695x; 1.0702x over previous
//
#include <hip/hip_runtime.h>
#include <hip/hip_bf16.h>

// channel_cluster_layer: pool -> fc1(sigmoid) -> fc2(sigmoid) -> weighted channel reduce
// B=32, C=2048, L=891 (9*11*9), P=8, HID=8192, NOUT=16384
// R5: fc latency-bound (VGPR=28, 3.6 TB/s). R6 depth-2 x 32k: only -10us.
// R8: 2 n-tiles x 64-k double-step, 12 loads/iter in named regs, split-K 16.
#define BB 32
#define CC 2048
#define LL 891
#define PP 8
#define HIDN 8192
#define NOUT 16384

typedef __attribute__((ext_vector_type(4))) float f32x4;
typedef __attribute__((ext_vector_type(8))) __bf16 bf16x8;

// ---------- kernel 1: global average pool, one wave per (b,c) row, float4 body ----------
__global__ __launch_bounds__(256) void pool_kernel(const float* __restrict__ x,
                                                   __hip_bfloat16* __restrict__ pooled) {
  int wid = threadIdx.x >> 6, lane = threadIdx.x & 63;
  int row = blockIdx.x * 4 + wid;  // < 65536
  const float* r = x + (long)row * LL;
  int align = (4 - ((row * 3) & 3)) & 3;       // scalar head elements (891%4==3)
  int nvec = (LL - align) >> 2;                // float4 count
  int rem = LL - align - (nvec << 2);          // scalar tail
  const f32x4* v = (const f32x4*)(r + align);
  float s = 0.f;
  for (int i = lane; i < nvec; i += 64) {
    f32x4 q = v[i];
    s += (q.x + q.y) + (q.z + q.w);
  }
  if (lane < align) s += r[lane];
  if (lane < rem) s += r[align + (nvec << 2) + lane];
#pragma unroll
  for (int off = 32; off > 0; off >>= 1) s += __shfl_xor(s, off);
  if (lane == 0) pooled[row] = __float2bfloat16(s * (1.0f / (float)LL));
}

// ---------- non-temporal 16B load ----------
__device__ __forceinline__ f32x4 ldnt(const float* p) {
  return __builtin_nontemporal_load((const f32x4*)p);
}

// f32x8 -> bf16x8 via native casts (compiler emits v_cvt_pk_bf16_f32, RNE)
__device__ __forceinline__ bf16x8 cvt8(f32x4 a, f32x4 b) {
  bf16x8 r;
  r[0] = (__bf16)a.x; r[1] = (__bf16)a.y; r[2] = (__bf16)a.z; r[3] = (__bf16)a.w;
  r[4] = (__bf16)b.x; r[5] = (__bf16)b.y; r[6] = (__bf16)b.z; r[7] = (__bf16)b.w;
  return r;
}

// ---------- kernels 2/4: partial[32][N] = A[32][K](bf16) @ W[N][K](f32->bf16)^T ----------
// Per wave: 2 n-tiles (n0, n0+64) x 64-k double-step. 8 W + 4 A loads per iter,
// all in named registers, depth-2 rotation -> ~12KB/wave in flight. 8 MFMA/iter.
// grid: (N/128, 16); block 256 = 4 waves.
__global__ __launch_bounds__(256) void fc_kernel(const __hip_bfloat16* __restrict__ A,
                                                 const float* __restrict__ W,
                                                 float* __restrict__ partial,
                                                 int N, int K, int kc) {
  int lane = threadIdx.x & 63, wv = threadIdx.x >> 6;
  int n0 = blockIdx.x * 128 + wv * 16;  // tile 0; tile 1 = n0+64
  int k0 = blockIdx.y * kc;
  int r = lane & 15, kg = lane >> 4;

  const float* Wp0 = W + (long)(n0 + r) * K + k0 + kg * 8;
  const float* Wp1 = Wp0 + 64 * (long)K;
  const __hip_bfloat16* Ap0 = A + (long)r * K + k0 + kg * 8;
  const __hip_bfloat16* Ap1 = Ap0 + 16 * (long)K;

  f32x4 acc00 = {0.f, 0.f, 0.f, 0.f};  // b 0-15  x tile0
  f32x4 acc01 = {0.f, 0.f, 0.f, 0.f};  // b 16-31 x tile0
  f32x4 acc10 = {0.f, 0.f, 0.f, 0.f};  // b 0-15  x tile1
  f32x4 acc11 = {0.f, 0.f, 0.f, 0.f};  // b 16-31 x tile1

  // current 64-k block registers: w{tile}{kstep}{half}, a{rowhalf}{kstep}
  f32x4 w000 = ldnt(Wp0), w001 = ldnt(Wp0 + 4);
  f32x4 w010 = ldnt(Wp0 + 32), w011 = ldnt(Wp0 + 36);
  f32x4 w100 = ldnt(Wp1), w101 = ldnt(Wp1 + 4);
  f32x4 w110 = ldnt(Wp1 + 32), w111 = ldnt(Wp1 + 36);
  int4 a00 = *(const int4*)(Ap0), a01 = *(const int4*)(Ap0 + 32);
  int4 a10 = *(const int4*)(Ap1), a11 = *(const int4*)(Ap1 + 32);

#define FC_COMPUTE()                                                            \
  {                                                                             \
    bf16x8 b00 = cvt8(w000, w001);                                              \
    bf16x8 b01 = cvt8(w010, w011);                                              \
    bf16x8 b10 = cvt8(w100, w101);                                              \
    bf16x8 b11 = cvt8(w110, w111);                                              \
    bf16x8 va00 = __builtin_bit_cast(bf16x8, a00);                              \
    bf16x8 va01 = __builtin_bit_cast(bf16x8, a01);                              \
    bf16x8 va10 = __builtin_bit_cast(bf16x8, a10);                              \
    bf16x8 va11 = __builtin_bit_cast(bf16x8, a11);                              \
    acc00 = __builtin_amdgcn_mfma_f32_16x16x32_bf16(va00, b00, acc00, 0, 0, 0); \
    acc01 = __builtin_amdgcn_mfma_f32_16x16x32_bf16(va10, b00, acc01, 0, 0, 0); \
    acc10 = __builtin_amdgcn_mfma_f32_16x16x32_bf16(va00, b10, acc10, 0, 0, 0); \
    acc11 = __builtin_amdgcn_mfma_f32_16x16x32_bf16(va10, b10, acc11, 0, 0, 0); \
    acc00 = __builtin_amdgcn_mfma_f32_16x16x32_bf16(va01, b01, acc00, 0, 0, 0); \
    acc01 = __builtin_amdgcn_mfma_f32_16x16x32_bf16(va11, b01, acc01, 0, 0, 0); \
    acc10 = __builtin_amdgcn_mfma_f32_16x16x32_bf16(va01, b11, acc10, 0, 0, 0); \
    acc11 = __builtin_amdgcn_mfma_f32_16x16x32_bf16(va11, b11, acc11, 0, 0, 0); \
  }

  for (int ks = 64; ks < kc; ks += 64) {
    // issue next 64-k block's 12 loads (depth-2)
    f32x4 nw000 = ldnt(Wp0 + ks), nw001 = ldnt(Wp0 + ks + 4);
    f32x4 nw010 = ldnt(Wp0 + ks + 32), nw011 = ldnt(Wp0 + ks + 36);
    f32x4 nw100 = ldnt(Wp1 + ks), nw101 = ldnt(Wp1 + ks + 4);
    f32x4 nw110 = ldnt(Wp1 + ks + 32), nw111 = ldnt(Wp1 + ks + 36);
    int4 na00 = *(const int4*)(Ap0 + ks), na01 = *(const int4*)(Ap0 + ks + 32);
    int4 na10 = *(const int4*)(Ap1 + ks), na11 = *(const int4*)(Ap1 + ks + 32);
    FC_COMPUTE();
    w000 = nw000; w001 = nw001; w010 = nw010; w011 = nw011;
    w100 = nw100; w101 = nw101; w110 = nw110; w111 = nw111;
    a00 = na00; a01 = na01; a10 = na10; a11 = na11;
  }
  FC_COMPUTE();
#undef FC_COMPUTE

  // C/D layout (m89-verified): col = lane&15 (-> n), row = (lane>>4)*4 + reg (-> b)
  long base = (long)blockIdx.y * 32 * N + n0 + r;
#pragma unroll
  for (int j = 0; j < 4; ++j) {
    int row = kg * 4 + j;
    partial[base + (long)row * N] = acc00[j];
    partial[base + (long)(row + 16) * N] = acc01[j];
    partial[base + 64 + (long)row * N] = acc10[j];
    partial[base + 64 + (long)(row + 16) * N] = acc11[j];
  }
}

// ---------- kernels 3/5: reduce splits + bias + sigmoid, float4-wide ----------
__global__ __launch_bounds__(256) void fc_reduce_kernel(const float* __restrict__ part,
                                                        int nsplit, int MN, int N,
                                                        const float* __restrict__ bias,
                                                        float* __restrict__ outF,
                                                        __hip_bfloat16* __restrict__ outB) {
  int i4 = blockIdx.x * 256 + threadIdx.x;  // MN/4 lanes
  if (i4 * 4 >= MN) return;
  f32x4 s = {0.f, 0.f, 0.f, 0.f};
  for (int i = 0; i < nsplit; ++i) {
    f32x4 v = *(const f32x4*)(part + (long)i * MN + i4 * 4);
    s += v;
  }
  f32x4 bv = *(const f32x4*)(bias + ((i4 * 4) & (N - 1)));
  f32x4 g;
  g.x = 1.f / (1.f + __expf(-(s.x + bv.x)));
  g.y = 1.f / (1.f + __expf(-(s.y + bv.y)));
  g.z = 1.f / (1.f + __expf(-(s.z + bv.z)));
  g.w = 1.f / (1.f + __expf(-(s.w + bv.w)));
  if (outF) *(f32x4*)(outF + i4 * 4) = g;
  if (outB) {
    union { __hip_bfloat16 h[4]; unsigned long long u; } pk;
    pk.h[0] = __float2bfloat16(g.x); pk.h[1] = __float2bfloat16(g.y);
    pk.h[2] = __float2bfloat16(g.z); pk.h[3] = __float2bfloat16(g.w);
    *((unsigned long long*)outB + i4) = pk.u;
  }
}

// ---------- kernel 6: weighted[b][p][l] partials = sum_c g[b][p*C+c] * x[b][c][l] ----------
__global__ __launch_bounds__(256) void ein_partial_kernel(const float* __restrict__ x,
                                                          const float* __restrict__ g,
                                                          float* __restrict__ part) {
  int l = blockIdx.x * 256 + threadIdx.x;
  int b = blockIdx.y;
  int s = blockIdx.z;
  int c0 = s * 256;
  const float* xp = x + ((long)b * CC + c0) * LL + l;
  const float* gp = g + (long)b * NOUT + c0;
  bool act = l < LL;
  float acc[PP] = {0.f, 0.f, 0.f, 0.f, 0.f, 0.f, 0.f, 0.f};
#pragma unroll 8
  for (int i = 0; i < 256; ++i) {
    float xv = act ? xp[(long)i * LL] : 0.f;
#pragma unroll
    for (int p = 0; p < PP; ++p) acc[p] += gp[p * CC + i] * xv;
  }
  if (act) {
    float* pp = part + (long)(s * BB + b) * PP * LL + l;
#pragma unroll
    for (int p = 0; p < PP; ++p) pp[(long)p * LL] = acc[p];
  }
}

// ---------- kernel 7: reduce c-splits, /C, float4-wide ----------
__global__ __launch_bounds__(256) void ein_reduce_kernel(const float* __restrict__ part,
                                                         float* __restrict__ outw) {
  int i4 = blockIdx.x * 256 + threadIdx.x;  // 57024 = 891*256/4 lanes
  if (i4 >= (BB * PP * LL) / 4) return;
  f32x4 s = {0.f, 0.f, 0.f, 0.f};
#pragma unroll
  for (int i = 0; i < 8; ++i) {
    f32x4 v = *(const f32x4*)(part + (long)i * (BB * PP * LL) + i4 * 4);
    s += v;
  }
  const float inv = 1.0f / (float)CC;
  f32x4 o = s * inv;
  *(f32x4*)(outw + i4 * 4) = o;
}

extern "C" void kernel_launch(void* const* d_in, const int* in_sizes, int n_in,
                              void* d_out, int out_size, void* d_ws, size_t ws_size,
                              hipStream_t stream) {
  const float* x     = (const float*)d_in[0];
  const float* fc1_w = (const float*)d_in[1];
  const float* fc1_b = (const float*)d_in[2];
  const float* fc2_w = (const float*)d_in[3];
  const float* fc2_b = (const float*)d_in[4];
  float* out = (float*)d_out;

  char* ws = (char*)d_ws;
  __hip_bfloat16* pooled = (__hip_bfloat16*)ws;              // 32*2048*2   = 128 KB
  __hip_bfloat16* hbuf   = (__hip_bfloat16*)(ws + 131072);   // 32*8192*2   = 512 KB
  float* part            = (float*)(ws + 655360);            // max 33.6 MB (reused per stage)

  pool_kernel<<<BB * CC / 4, 256, 0, stream>>>(x, pooled);

  // fc1: N=8192, K=2048, 16-way split-K (kc=128) -> 1024 blocks
  fc_kernel<<<dim3(HIDN / 128, 16), 256, 0, stream>>>(pooled, fc1_w, part, HIDN, CC, CC / 16);
  fc_reduce_kernel<<<BB * HIDN / 1024, 256, 0, stream>>>(part, 16, BB * HIDN, HIDN, fc1_b,
                                                         nullptr, hbuf);

  // fc2: N=16384, K=8192, 16-way split-K (kc=512) -> 2048 blocks
  fc_kernel<<<dim3(NOUT / 128, 16), 256, 0, stream>>>(hbuf, fc2_w, part, NOUT, HIDN, HIDN / 16);
  fc_reduce_kernel<<<BB * NOUT / 1024, 256, 0, stream>>>(part, 16, BB * NOUT, NOUT, fc2_b,
                                                         out, nullptr);

  ein_partial_kernel<<<dim3(4, BB, 8), 256, 0, stream>>>(x, out, part);
  ein_reduce_kernel<<<(BB * PP * LL / 4 + 255) / 256, 256, 0, stream>>>(part, out + BB * PP * CC);
}